// Round 14
// baseline (159.486 us; speedup 1.0000x reference)
//
#include <hip/hip_runtime.h>
#include <stdint.h>

// Problem constants
#define NROWS 32768
#define NMQ   (NROWS * 256)       // per-book soft_prob elements
#define QSIZE (NROWS * 256)

typedef __attribute__((ext_vector_type(8))) short short8;   // 8 bf16 (4 VGPR)
typedef __attribute__((ext_vector_type(4))) float f32x4;    // MFMA acc

#define LOG2E 1.4426950408889634f

// JAX partitionable threefry: bits[i] = x0^x1 of threefry2x32((0,42),(0,i)).
// Verified exact rounds 3-13. Outlined (neutral perf, smaller code);
// two interleaved chains per call preserve ILP.
__device__ __attribute__((noinline)) uint2 tf2x(uint32_t ia, uint32_t ib) {
    const uint32_t K1 = 42u;
    const uint32_t K2 = 0x1BD11BDAu ^ 42u;
    uint32_t a0 = 0u, a1 = ia + K1;
    uint32_t b0 = 0u, b1 = ib + K1;
#define TFR2(r) { a0 += a1; a1 = __builtin_rotateleft32(a1,(r)) ^ a0; \
                  b0 += b1; b1 = __builtin_rotateleft32(b1,(r)) ^ b0; }
    TFR2(13) TFR2(15) TFR2(26) TFR2(6)
    a0 += K1; a1 += K2 + 1u;  b0 += K1; b1 += K2 + 1u;
    TFR2(17) TFR2(29) TFR2(16) TFR2(24)
    a0 += K2; a1 += 2u;       b0 += K2; b1 += 2u;
    TFR2(13) TFR2(15) TFR2(26) TFR2(6)
    a1 += K1 + 3u;            b1 += K1 + 3u;
    TFR2(17) TFR2(29) TFR2(16) TFR2(24)
    a0 += K1; a1 += K2 + 4u;  b0 += K1; b1 += K2 + 4u;
    TFR2(13) TFR2(15) TFR2(26) TFR2(6)
    a0 += K2; a1 += 5u;       b0 += K2; b1 += 5u;
#undef TFR2
    return make_uint2(a0 ^ a1, b0 ^ b1);
}

__device__ __forceinline__ float u01f(uint32_t b) {
    return __uint_as_float((b >> 9) | 0x3F800000u) - 1.0f;
}

// split f32 -> bf16 hi (truncate) + bf16 lo (remainder) for f32-class MFMA dot
__device__ __forceinline__ void split8(const float* p, short8& h, short8& l) {
#pragma unroll
    for (int e = 0; e < 8; ++e) {
        float f = p[e];
        uint32_t ib = __float_as_uint(f);
        h[e] = (short)(ib >> 16);
        float fh = __uint_as_float(ib & 0xFFFF0000u);
        l[e] = (short)(__float_as_uint(f - fh) >> 16);
    }
}

// f32 -> bf16 round-to-nearest-even (staging only)
__device__ __forceinline__ unsigned short bf16rne(float f) {
    uint32_t ib = __float_as_uint(f);
    uint32_t r = ib + 0x7FFFu + ((ib >> 16) & 1u);
    return (unsigned short)(r >> 16);
}

// All-lanes 16-lane-group reduction on the VALU pipe (DPP), zero LDS.
#define DPPX(x, ctrl) \
    __int_as_float(__builtin_amdgcn_update_dpp(__float_as_int(x), \
        __float_as_int(x), (ctrl), 0xf, 0xf, false))

__device__ __forceinline__ float red16_max(float x) {
    x = fmaxf(x, DPPX(x, 0xB1));    // quad_perm [1,0,3,2]
    x = fmaxf(x, DPPX(x, 0x4E));    // quad_perm [2,3,0,1]
    x = fmaxf(x, DPPX(x, 0x141));   // row_half_mirror
    x = fmaxf(x, DPPX(x, 0x140));   // row_mirror
    return x;
}
__device__ __forceinline__ float red16_sum(float x) {
    x += DPPX(x, 0xB1);
    x += DPPX(x, 0x4E);
    x += DPPX(x, 0x141);
    x += DPPX(x, 0x140);
    return x;
}

__global__ __launch_bounds__(512, 4)
void pq_fused(const float* __restrict__ X, const float* __restrict__ C,
              float* __restrict__ out)
{
    // LDS: 16K + 16K + 16K + 32K = 81920 B exactly -> 2 blocks/CU
    __shared__ short8 CBH[16 * 64];          // logits B-frags hi  [tile][lane]
    __shared__ short8 CBL[16 * 64];          // logits B-frags lo
    __shared__ short8 CQB[16 * 64];          // Q B-frags bf16 [ch*2+lt][lane]
    __shared__ __align__(16) unsigned short PL[8][8][256];  // p chunk rows bf16, tt^g swz
    // C2T (||c_m||^2, 1 KB) unioned into PL[0][0..1]; consumed before first PL write
    float* C2T = reinterpret_cast<float*>(&PL[0][0][0]);

    const int t    = threadIdx.x;
    const int wv   = t >> 6;
    const int lane = t & 63;
    const int g    = lane >> 4;              // k-slice group / row group
    const int c    = lane & 15;              // m-within-tile / A-row
    const int b      = blockIdx.x & 7;       // book
    const int rowblk = blockIdx.x >> 3;      // 0..127, 256 rows each

    // ---- stage logits B-frags (R9-verified layout) ----
    for (int i = t; i < 1024; i += 512) {
        const int tile = i >> 6, l = i & 63;
        const int m = tile * 16 + (l & 15);
        const int kb = (l >> 4) * 8;
        const float* cp = C + (size_t)m * 256 + b * 32 + kb;
        float buf[8];
        *reinterpret_cast<float4*>(&buf[0]) = *reinterpret_cast<const float4*>(cp);
        *reinterpret_cast<float4*>(&buf[4]) = *reinterpret_cast<const float4*>(cp + 4);
        short8 h, lo;
        split8(buf, h, lo);
        CBH[i] = h;
        CBL[i] = lo;
    }
    // ---- stage Q B-frags: CQB[ch*2+lt][lane(gg,cc)][e] = bf16(C[ch*32+gg*8+e][lt*16+cc]) ----
    for (int i = t; i < 1024; i += 512) {
        const int ch = i >> 7, lt = (i >> 6) & 1, l = i & 63;
        const int gg = l >> 4, cc = l & 15;
        short8 v;
#pragma unroll
        for (int e = 0; e < 8; ++e)
            v[e] = (short)bf16rne(C[(size_t)(ch * 32 + gg * 8 + e) * 256 + b * 32 + lt * 16 + cc]);
        CQB[i] = v;
    }
    // ---- c2 table (into PL-overlap region) ----
    if (t < 256) {
        const float* cp = C + (size_t)t * 256 + b * 32;
        float s = 0.f;
#pragma unroll
        for (int q = 0; q < 8; ++q) {
            float4 v = *reinterpret_cast<const float4*>(cp + q * 4);
            s = fmaf(v.x, v.x, fmaf(v.y, v.y, fmaf(v.z, v.z, fmaf(v.w, v.w, s))));
        }
        C2T[t] = s;
    }
    __syncthreads();

    // bias[tile] = -2*log2e*c2[tile*16+c]  (z in exp2 domain)
    float bias[16];
#pragma unroll
    for (int tt = 0; tt < 16; ++tt)
        bias[tt] = -2.0f * LOG2E * C2T[tt * 16 + c];
    __syncthreads();    // all lanes done reading C2T before PL writes clobber it

    float* __restrict__ Qout = out;
    float* __restrict__ SP   = out + QSIZE;

    // 2 iterations x (8 waves x 16 rows) = 256 rows per block
    for (int it = 0; it < 2; ++it) {
        const int r0 = (rowblk << 8) + (it << 7) + (wv << 4);

        // ---- A-frags from global X: lane = row c, k-slice g*8..+7 ----
        short8 xh, xl;
        {
            const float* xp = X + (size_t)(r0 + c) * 256 + b * 32 + g * 8;
            float buf[8];
            *reinterpret_cast<float4*>(&buf[0]) = *reinterpret_cast<const float4*>(xp);
            *reinterpret_cast<float4*>(&buf[4]) = *reinterpret_cast<const float4*>(xp + 4);
            split8(buf, xh, xl);
        }

        // ---- logits MFMA (split-bf16) INTERLEAVED with j=0 threefry calls:
        //      MFMA pipe and VALU pipe are separate; the RNG VALU work fills
        //      the otherwise-idle VALU during the synchronized MFMA phase. ----
        f32x4 acc[16];
        uint32_t u0h[16];
        const uint32_t base0 = (uint32_t)b * (uint32_t)NMQ
                             + (uint32_t)(r0 + g * 4) * 256u + (uint32_t)c;
#pragma unroll
        for (int th = 0; th < 8; ++th) {
#pragma unroll
            for (int q = 0; q < 2; ++q) {
                const int tt = th * 2 + q;
                short8 bh = CBH[tt * 64 + lane];
                short8 bl = CBL[tt * 64 + lane];
                f32x4 a = {0.f, 0.f, 0.f, 0.f};
                a = __builtin_amdgcn_mfma_f32_16x16x32_bf16(xh, bh, a, 0, 0, 0);
                a = __builtin_amdgcn_mfma_f32_16x16x32_bf16(xl, bh, a, 0, 0, 0);
                a = __builtin_amdgcn_mfma_f32_16x16x32_bf16(xh, bl, a, 0, 0, 0);
                acc[tt] = a;
            }
            uint2 rr = tf2x(base0 + (uint32_t)(th * 16),
                            base0 + (uint32_t)(th * 16 + 128));
            u0h[th] = rr.x;
            u0h[th + 8] = rr.y;
        }

        // ---- j=0: softmax+gumbel+p using the pre-computed u0h bits ----
        {
            const int n = r0 + g * 4;
            float z[16];
            float mx0 = -3.4e38f, mx1 = -3.4e38f;
#pragma unroll
            for (int tt = 0; tt < 8; ++tt) {
                float u0  = u01f(u0h[tt]);
                float tg0 = -__log2f(u0 + 1e-20f);
                float z0  = fmaf(acc[tt][0], 4.0f * LOG2E, bias[tt])
                          - 2.0f * __log2f(tg0);
                z[tt] = z0; mx0 = fmaxf(mx0, z0);
                float u1  = u01f(u0h[tt + 8]);
                float tg1 = -__log2f(u1 + 1e-20f);
                float z1  = fmaf(acc[tt + 8][0], 4.0f * LOG2E, bias[tt + 8])
                          - 2.0f * __log2f(tg1);
                z[tt + 8] = z1; mx1 = fmaxf(mx1, z1);
            }
            const float mx = red16_max(fmaxf(mx0, mx1));
            float s0 = 0.f, s1 = 0.f;
#pragma unroll
            for (int tt = 0; tt < 8; ++tt) {
                float e0 = __builtin_amdgcn_exp2f(z[tt] - mx);
                float e1 = __builtin_amdgcn_exp2f(z[tt + 8] - mx);
                z[tt] = e0; s0 += e0;
                z[tt + 8] = e1; s1 += e1;
            }
            const float s = red16_sum(s0 + s1);
            const float rs = __builtin_amdgcn_rcpf(s);
            float* spg = SP + (size_t)b * NMQ + (size_t)n * 256 + c;
            unsigned short* plrow = &PL[wv][g * 2][0];
#pragma unroll
            for (int tt = 0; tt < 16; ++tt) {
                float p = z[tt] * rs;
                __builtin_nontemporal_store(p, spg + tt * 16);
                plrow[((tt ^ g) << 4) + c] =
                    reinterpret_cast<const unsigned short*>(&p)[1];
            }
        }

        // ---- j=1..3: softmax+gumbel+p with inline tf2x calls ----
#define PROCJ(jj)                                                               \
        {                                                                       \
            const int n = r0 + g * 4 + (jj);                                    \
            const uint32_t base = (uint32_t)b * (uint32_t)NMQ                   \
                                + (uint32_t)n * 256u + (uint32_t)c;             \
            float z[16];                                                        \
            float mx0 = -3.4e38f, mx1 = -3.4e38f;                               \
            _Pragma("unroll")                                                   \
            for (int tt = 0; tt < 8; ++tt) {                                    \
                uint2 rr = tf2x(base + (uint32_t)(tt * 16),                     \
                                base + (uint32_t)(tt * 16 + 128));              \
                float u0  = u01f(rr.x);                                         \
                float tg0 = -__log2f(u0 + 1e-20f);                              \
                float z0  = fmaf(acc[tt][(jj)], 4.0f * LOG2E, bias[tt])         \
                          - 2.0f * __log2f(tg0);                                \
                z[tt] = z0; mx0 = fmaxf(mx0, z0);                               \
                float u1  = u01f(rr.y);                                         \
                float tg1 = -__log2f(u1 + 1e-20f);                              \
                float z1  = fmaf(acc[tt + 8][(jj)], 4.0f * LOG2E, bias[tt + 8]) \
                          - 2.0f * __log2f(tg1);                                \
                z[tt + 8] = z1; mx1 = fmaxf(mx1, z1);                           \
            }                                                                   \
            const float mx = red16_max(fmaxf(mx0, mx1));                        \
            float s0 = 0.f, s1 = 0.f;                                           \
            _Pragma("unroll")                                                   \
            for (int tt = 0; tt < 8; ++tt) {                                    \
                float e0 = __builtin_amdgcn_exp2f(z[tt] - mx);                  \
                float e1 = __builtin_amdgcn_exp2f(z[tt + 8] - mx);              \
                z[tt] = e0; s0 += e0;                                           \
                z[tt + 8] = e1; s1 += e1;                                       \
            }                                                                   \
            const float s = red16_sum(s0 + s1);                                 \
            const float rs = __builtin_amdgcn_rcpf(s);                          \
            float* spg = SP + (size_t)b * NMQ + (size_t)n * 256 + c;            \
            unsigned short* plrow = &PL[wv][g * 2 + ((jj) & 1)][0];             \
            _Pragma("unroll")                                                   \
            for (int tt = 0; tt < 16; ++tt) {                                   \
                float p = z[tt] * rs;                                           \
                __builtin_nontemporal_store(p, spg + tt * 16);                  \
                plrow[((tt ^ g) << 4) + c] =                                    \
                    reinterpret_cast<const unsigned short*>(&p)[1];             \
            }                                                                   \
        }

        // ---- Q MFMA on an 8-row chunk (A rows 8..15 garbage, discarded) ----
#define QCHUNK(joff)                                                            \
        {                                                                       \
            f32x4 q0 = {0.f, 0.f, 0.f, 0.f};                                    \
            f32x4 q1 = {0.f, 0.f, 0.f, 0.f};                                    \
            _Pragma("unroll")                                                   \
            for (int ch = 0; ch < 8; ++ch) {                                    \
                const int ttp = (ch * 2 + (g >> 1)) ^ ((c & 7) >> 1);           \
                const short8 pa = *reinterpret_cast<const short8*>(             \
                    &PL[wv][c & 7][ttp * 16 + (g & 1) * 8]);                    \
                q0 = __builtin_amdgcn_mfma_f32_16x16x32_bf16(                   \
                         pa, CQB[(ch * 2 + 0) * 64 + lane], q0, 0, 0, 0);       \
                q1 = __builtin_amdgcn_mfma_f32_16x16x32_bf16(                   \
                         pa, CQB[(ch * 2 + 1) * 64 + lane], q1, 0, 0, 0);       \
            }                                                                   \
            if (g < 2) {                                                        \
                _Pragma("unroll")                                               \
                for (int reg = 0; reg < 4; ++reg) {                             \
                    const int rl = g * 4 + reg;                                 \
                    const int n = r0 + ((rl >> 1) << 2) + (rl & 1) + (joff);    \
                    float* qp = Qout + (size_t)n * 256 + b * 32 + c;            \
                    __builtin_nontemporal_store(q0[reg], qp);                   \
                    __builtin_nontemporal_store(q1[reg], qp + 16);              \
                }                                                               \
            }                                                                   \
        }

        PROCJ(1) QCHUNK(0)
        PROCJ(2) PROCJ(3) QCHUNK(2)
#undef PROCJ
#undef QCHUNK
        // wave-private PL: per-wave DS ops are in-order; no barrier needed
    }
}

extern "C" void kernel_launch(void* const* d_in, const int* in_sizes, int n_in,
                              void* d_out, int out_size, void* d_ws, size_t ws_size,
                              hipStream_t stream) {
    const float* X = (const float*)d_in[0];
    const float* C = (const float*)d_in[1];
    float* out = (float*)d_out;

    dim3 grid(1024);   // 8 books x 128 row-blocks (256 rows each)
    dim3 block(512);
    hipLaunchKernelGGL(pq_fused, grid, block, 0, stream, X, C, out);
}

// Round 15
// 155.279 us; speedup vs baseline: 1.0271x; 1.0271x over previous
//
#include <hip/hip_runtime.h>
#include <stdint.h>

// Problem constants
#define NROWS 32768
#define NMQ   (NROWS * 256)       // per-book soft_prob elements
#define QSIZE (NROWS * 256)

typedef __attribute__((ext_vector_type(8))) short short8;   // 8 bf16 (4 VGPR)
typedef __attribute__((ext_vector_type(4))) float f32x4;    // MFMA acc

#define LOG2E 1.4426950408889634f

// JAX partitionable threefry: bits[i] = x0^x1 of threefry2x32((0,42),(0,i)).
// Verified exact rounds 3-14. Outlined (neutral perf, smaller code);
// two interleaved chains per call preserve ILP.
__device__ __attribute__((noinline)) uint2 tf2x(uint32_t ia, uint32_t ib) {
    const uint32_t K1 = 42u;
    const uint32_t K2 = 0x1BD11BDAu ^ 42u;
    uint32_t a0 = 0u, a1 = ia + K1;
    uint32_t b0 = 0u, b1 = ib + K1;
#define TFR2(r) { a0 += a1; a1 = __builtin_rotateleft32(a1,(r)) ^ a0; \
                  b0 += b1; b1 = __builtin_rotateleft32(b1,(r)) ^ b0; }
    TFR2(13) TFR2(15) TFR2(26) TFR2(6)
    a0 += K1; a1 += K2 + 1u;  b0 += K1; b1 += K2 + 1u;
    TFR2(17) TFR2(29) TFR2(16) TFR2(24)
    a0 += K2; a1 += 2u;       b0 += K2; b1 += 2u;
    TFR2(13) TFR2(15) TFR2(26) TFR2(6)
    a1 += K1 + 3u;            b1 += K1 + 3u;
    TFR2(17) TFR2(29) TFR2(16) TFR2(24)
    a0 += K1; a1 += K2 + 4u;  b0 += K1; b1 += K2 + 4u;
    TFR2(13) TFR2(15) TFR2(26) TFR2(6)
    a0 += K2; a1 += 5u;       b0 += K2; b1 += 5u;
#undef TFR2
    return make_uint2(a0 ^ a1, b0 ^ b1);
}

__device__ __forceinline__ float u01f(uint32_t b) {
    return __uint_as_float((b >> 9) | 0x3F800000u) - 1.0f;
}

// split f32 -> bf16 hi (truncate) + bf16 lo (remainder) for f32-class MFMA dot
__device__ __forceinline__ void split8(const float* p, short8& h, short8& l) {
#pragma unroll
    for (int e = 0; e < 8; ++e) {
        float f = p[e];
        uint32_t ib = __float_as_uint(f);
        h[e] = (short)(ib >> 16);
        float fh = __uint_as_float(ib & 0xFFFF0000u);
        l[e] = (short)(__float_as_uint(f - fh) >> 16);
    }
}

// f32 -> bf16 round-to-nearest-even (staging only)
__device__ __forceinline__ unsigned short bf16rne(float f) {
    uint32_t ib = __float_as_uint(f);
    uint32_t r = ib + 0x7FFFu + ((ib >> 16) & 1u);
    return (unsigned short)(r >> 16);
}

// All-lanes 16-lane-group reduction on the VALU pipe (DPP), zero LDS.
#define DPPX(x, ctrl) \
    __int_as_float(__builtin_amdgcn_update_dpp(__float_as_int(x), \
        __float_as_int(x), (ctrl), 0xf, 0xf, false))

__device__ __forceinline__ float red16_max(float x) {
    x = fmaxf(x, DPPX(x, 0xB1));    // quad_perm [1,0,3,2]
    x = fmaxf(x, DPPX(x, 0x4E));    // quad_perm [2,3,0,1]
    x = fmaxf(x, DPPX(x, 0x141));   // row_half_mirror
    x = fmaxf(x, DPPX(x, 0x140));   // row_mirror
    return x;
}
__device__ __forceinline__ float red16_sum(float x) {
    x += DPPX(x, 0xB1);
    x += DPPX(x, 0x4E);
    x += DPPX(x, 0x141);
    x += DPPX(x, 0x140);
    return x;
}

__global__ __launch_bounds__(512, 4)
void pq_fused(const float* __restrict__ X, const float* __restrict__ C,
              float* __restrict__ out)
{
    // LDS: 16K + 16K + 16K + 32K = 81920 B exactly -> 2 blocks/CU, 4 waves/SIMD
    __shared__ short8 CBH[16 * 64];          // logits B-frags hi  [tile][lane]
    __shared__ short8 CBL[16 * 64];          // logits B-frags lo
    __shared__ short8 CQB[16 * 64];          // Q B-frags bf16 [ch*2+lt][lane]
    __shared__ __align__(16) unsigned short PL[8][8][256];  // p chunk rows bf16, tt^g swz
    // C2T (||c_m||^2, 1 KB) unioned into PL[0][0..1]; consumed before first PL write
    float* C2T = reinterpret_cast<float*>(&PL[0][0][0]);

    const int t    = threadIdx.x;
    const int wv   = t >> 6;
    const int lane = t & 63;
    const int g    = lane >> 4;              // k-slice group / row group
    const int c    = lane & 15;              // m-within-tile / A-row
    const int b      = blockIdx.x & 7;       // book
    const int rowblk = blockIdx.x >> 3;      // 0..127, 256 rows each

    // ---- stage logits B-frags (R9-verified layout) ----
    for (int i = t; i < 1024; i += 512) {
        const int tile = i >> 6, l = i & 63;
        const int m = tile * 16 + (l & 15);
        const int kb = (l >> 4) * 8;
        const float* cp = C + (size_t)m * 256 + b * 32 + kb;
        float buf[8];
        *reinterpret_cast<float4*>(&buf[0]) = *reinterpret_cast<const float4*>(cp);
        *reinterpret_cast<float4*>(&buf[4]) = *reinterpret_cast<const float4*>(cp + 4);
        short8 h, lo;
        split8(buf, h, lo);
        CBH[i] = h;
        CBL[i] = lo;
    }
    // ---- stage Q B-frags: CQB[ch*2+lt][lane(gg,cc)][e] = bf16(C[ch*32+gg*8+e][lt*16+cc]) ----
    for (int i = t; i < 1024; i += 512) {
        const int ch = i >> 7, lt = (i >> 6) & 1, l = i & 63;
        const int gg = l >> 4, cc = l & 15;
        short8 v;
#pragma unroll
        for (int e = 0; e < 8; ++e)
            v[e] = (short)bf16rne(C[(size_t)(ch * 32 + gg * 8 + e) * 256 + b * 32 + lt * 16 + cc]);
        CQB[i] = v;
    }
    // ---- c2 table (into PL-overlap region) ----
    if (t < 256) {
        const float* cp = C + (size_t)t * 256 + b * 32;
        float s = 0.f;
#pragma unroll
        for (int q = 0; q < 8; ++q) {
            float4 v = *reinterpret_cast<const float4*>(cp + q * 4);
            s = fmaf(v.x, v.x, fmaf(v.y, v.y, fmaf(v.z, v.z, fmaf(v.w, v.w, s))));
        }
        C2T[t] = s;
    }
    __syncthreads();

    // bias[tile] = -2*log2e*c2[tile*16+c]  (z in exp2 domain)
    float bias[16];
#pragma unroll
    for (int tt = 0; tt < 16; ++tt)
        bias[tt] = -2.0f * LOG2E * C2T[tt * 16 + c];
    __syncthreads();    // all lanes done reading C2T before PL writes clobber it

    float* __restrict__ Qout = out;
    float* __restrict__ SP   = out + QSIZE;

    // 2 iterations x (8 waves x 16 rows) = 256 rows per block
    for (int it = 0; it < 2; ++it) {
        const int r0 = (rowblk << 8) + (it << 7) + (wv << 4);

        // ---- A-frags from global X: lane = row c, k-slice g*8..+7 ----
        short8 xh, xl;
        {
            const float* xp = X + (size_t)(r0 + c) * 256 + b * 32 + g * 8;
            float buf[8];
            *reinterpret_cast<float4*>(&buf[0]) = *reinterpret_cast<const float4*>(xp);
            *reinterpret_cast<float4*>(&buf[4]) = *reinterpret_cast<const float4*>(xp + 4);
            split8(buf, xh, xl);
        }

        // ---- logits MFMA (split-bf16, R9-verified) ----
        f32x4 acc[16];
#pragma unroll
        for (int tt = 0; tt < 16; ++tt) {
            short8 bh = CBH[tt * 64 + lane];
            short8 bl = CBL[tt * 64 + lane];
            f32x4 a = {0.f, 0.f, 0.f, 0.f};
            a = __builtin_amdgcn_mfma_f32_16x16x32_bf16(xh, bh, a, 0, 0, 0);
            a = __builtin_amdgcn_mfma_f32_16x16x32_bf16(xl, bh, a, 0, 0, 0);
            a = __builtin_amdgcn_mfma_f32_16x16x32_bf16(xh, bl, a, 0, 0, 0);
            acc[tt] = a;
        }

        // ---- per-j softmax+gumbel+p; threefry via outlined 2-chain calls ----
#define PROCJ(jj)                                                               \
        {                                                                       \
            const int n = r0 + g * 4 + (jj);                                    \
            const uint32_t base = (uint32_t)b * (uint32_t)NMQ                   \
                                + (uint32_t)n * 256u + (uint32_t)c;             \
            float z[16];                                                        \
            float mx0 = -3.4e38f, mx1 = -3.4e38f;                               \
            _Pragma("unroll")                                                   \
            for (int tt = 0; tt < 8; ++tt) {                                    \
                uint2 rr = tf2x(base + (uint32_t)(tt * 16),                     \
                                base + (uint32_t)(tt * 16 + 128));              \
                float u0  = u01f(rr.x);                                         \
                float tg0 = -__log2f(u0 + 1e-20f);                              \
                float z0  = fmaf(acc[tt][(jj)], 4.0f * LOG2E, bias[tt])         \
                          - 2.0f * __log2f(tg0);                                \
                z[tt] = z0; mx0 = fmaxf(mx0, z0);                               \
                float u1  = u01f(rr.y);                                         \
                float tg1 = -__log2f(u1 + 1e-20f);                              \
                float z1  = fmaf(acc[tt + 8][(jj)], 4.0f * LOG2E, bias[tt + 8]) \
                          - 2.0f * __log2f(tg1);                                \
                z[tt + 8] = z1; mx1 = fmaxf(mx1, z1);                           \
            }                                                                   \
            const float mx = red16_max(fmaxf(mx0, mx1));                        \
            float s0 = 0.f, s1 = 0.f;                                           \
            _Pragma("unroll")                                                   \
            for (int tt = 0; tt < 8; ++tt) {                                    \
                float e0 = __builtin_amdgcn_exp2f(z[tt] - mx);                  \
                float e1 = __builtin_amdgcn_exp2f(z[tt + 8] - mx);              \
                z[tt] = e0; s0 += e0;                                           \
                z[tt + 8] = e1; s1 += e1;                                       \
            }                                                                   \
            const float s = red16_sum(s0 + s1);                                 \
            const float rs = __builtin_amdgcn_rcpf(s);                          \
            float* spg = SP + (size_t)b * NMQ + (size_t)n * 256 + c;            \
            unsigned short* plrow = &PL[wv][g * 2 + ((jj) & 1)][0];             \
            _Pragma("unroll")                                                   \
            for (int tt = 0; tt < 16; ++tt) {                                   \
                float p = z[tt] * rs;                                           \
                __builtin_nontemporal_store(p, spg + tt * 16);                  \
                plrow[((tt ^ g) << 4) + c] =                                    \
                    reinterpret_cast<const unsigned short*>(&p)[1];             \
            }                                                                   \
        }

        // ---- Q MFMA on an 8-row chunk (A rows 8..15 garbage, discarded) ----
#define QCHUNK(joff)                                                            \
        {                                                                       \
            f32x4 q0 = {0.f, 0.f, 0.f, 0.f};                                    \
            f32x4 q1 = {0.f, 0.f, 0.f, 0.f};                                    \
            _Pragma("unroll")                                                   \
            for (int ch = 0; ch < 8; ++ch) {                                    \
                const int ttp = (ch * 2 + (g >> 1)) ^ ((c & 7) >> 1);           \
                const short8 pa = *reinterpret_cast<const short8*>(             \
                    &PL[wv][c & 7][ttp * 16 + (g & 1) * 8]);                    \
                q0 = __builtin_amdgcn_mfma_f32_16x16x32_bf16(                   \
                         pa, CQB[(ch * 2 + 0) * 64 + lane], q0, 0, 0, 0);       \
                q1 = __builtin_amdgcn_mfma_f32_16x16x32_bf16(                   \
                         pa, CQB[(ch * 2 + 1) * 64 + lane], q1, 0, 0, 0);       \
            }                                                                   \
            if (g < 2) {                                                        \
                _Pragma("unroll")                                               \
                for (int reg = 0; reg < 4; ++reg) {                             \
                    const int rl = g * 4 + reg;                                 \
                    const int n = r0 + ((rl >> 1) << 2) + (rl & 1) + (joff);    \
                    float* qp = Qout + (size_t)n * 256 + b * 32 + c;            \
                    __builtin_nontemporal_store(q0[reg], qp);                   \
                    __builtin_nontemporal_store(q1[reg], qp + 16);              \
                }                                                               \
            }                                                                   \
        }

        PROCJ(0) PROCJ(1) QCHUNK(0)
        PROCJ(2) PROCJ(3) QCHUNK(2)
#undef PROCJ
#undef QCHUNK
        // wave-private PL: per-wave DS ops are in-order; no barrier needed
    }
}

extern "C" void kernel_launch(void* const* d_in, const int* in_sizes, int n_in,
                              void* d_out, int out_size, void* d_ws, size_t ws_size,
                              hipStream_t stream) {
    const float* X = (const float*)d_in[0];
    const float* C = (const float*)d_in[1];
    float* out = (float*)d_out;

    dim3 grid(1024);   // 8 books x 128 row-blocks (256 rows each)
    dim3 block(512);
    hipLaunchKernelGGL(pq_fused, grid, block, 0, stream, X, C, out);
}